// Round 6
// baseline (194.993 us; speedup 1.0000x reference)
//
#include <hip/hip_runtime.h>
#include <hip/hip_bf16.h>

// RetrieverBase: q[64][32][128] f32, p[128][180][128] f32
// out = concat(term_relevance[64][128][32][180], query_maxsim[64][128][32], relevance[64][128])
#define A_N 64
#define B_N 128
#define Q_N 32
#define D_N 180
#define V_N 128

typedef __attribute__((ext_vector_type(8))) short bf16x8;   // 8 bf16 (4 VGPRs)
typedef __attribute__((ext_vector_type(4))) float f32x4;

__device__ __forceinline__ short f2bf(float f) {
  __hip_bfloat16 h = __float2bfloat16(f);
  return (short)__builtin_bit_cast(unsigned short, h);
}

__device__ __forceinline__ bf16x8 pack8(const f32x4& lo, const f32x4& hi) {
  bf16x8 v;
  v[0] = f2bf(lo[0]); v[1] = f2bf(lo[1]); v[2] = f2bf(lo[2]); v[3] = f2bf(lo[3]);
  v[4] = f2bf(hi[0]); v[5] = f2bf(hi[1]); v[6] = f2bf(hi[2]); v[7] = f2bf(hi[3]);
  return v;
}

// Grid 4096 = 64 bg x 64 a (a fast: consecutive blocks share p[bg*2..+2) and
// round-robin the 8 XCDs). Block = 4 INDEPENDENT waves: wave = (b-of-2, q-half).
// Each wave owns a contiguous, 64B-aligned 11520B output slice (16 q rows x
// 720B) and walks d-tiles 0..11 sequentially, storing straight from the MFMA
// accumulators: line-straddling chunks at dt boundaries are completed by the
// SAME wave one iteration later (~150 cy) -> L2 write-back merges to full
// lines. NO barriers in the hot path (R5's per-pair __syncthreads drained
// vmcnt and made the write stream bursty at 2 TB/s); one tiny end-of-block
// barrier combines the 2-float relevance halves.
__global__ __launch_bounds__(256, 4) void score_kernel(
    const float* __restrict__ q, const float* __restrict__ p,
    float* __restrict__ out) {
  const int bid  = blockIdx.x;
  const int a    = bid & 63;
  const int bg   = bid >> 6;          // 0..63 -> b pair {2bg, 2bg+1}
  const int tid  = threadIdx.x;
  const int wv   = tid >> 6;          // 0..3
  const int lane = tid & 63;
  const int l16  = lane & 15;
  const int g    = lane >> 4;         // 0..3
  const int b    = bg * 2 + (wv >> 1);
  const int qh   = wv & 1;            // q-half: rows qh*16 .. +15

  const float* __restrict__ qa = q + ((size_t)a * Q_N + qh * 16) * V_N;
  const float* __restrict__ pb = p + (size_t)b * D_N * V_N;

  // q as B-fragments for this wave's 16 q rows: B[k][col=q];
  // lane reads q[qh*16 + l16][kk*32 + g*8 ..+7]
  bf16x8 qf[4];
#pragma unroll
  for (int kk = 0; kk < 4; ++kk) {
    const float* s = qa + (size_t)l16 * V_N + kk * 32 + g * 8;
    qf[kk] = pack8(*reinterpret_cast<const f32x4*>(s),
                   *reinterpret_cast<const f32x4*>(s + 4));
  }

#define LOADRAW(dst, dt)                                                     \
  {                                                                          \
    const int drow = (dt) * 16 + l16;                                        \
    const int dr   = drow < D_N ? drow : (D_N - 1);                          \
    const float* s = pb + (size_t)dr * V_N + g * 8;                          \
    _Pragma("unroll")                                                        \
    for (int kk = 0; kk < 4; ++kk) {                                         \
      dst[2 * kk]     = *reinterpret_cast<const f32x4*>(s + kk * 32);        \
      dst[2 * kk + 1] = *reinterpret_cast<const f32x4*>(s + kk * 32 + 4);    \
    }                                                                        \
  }

  f32x4 rawA[8], rawB[8];
  LOADRAW(rawA, 0);

  float qm = -INFINITY;
  // lane's output row base: (a,b) region + row q = qh*16 + l16
  const size_t outbase =
      ((size_t)a * B_N + b) * (size_t)(Q_N * D_N) + (size_t)(qh * 16 + l16) * D_N;

#pragma unroll
  for (int dt = 0; dt < 12; ++dt) {
    f32x4* cur = (dt & 1) ? rawB : rawA;   // dt compile-time (full unroll)
    f32x4* nxt = (dt & 1) ? rawA : rawB;
    if (dt < 11) LOADRAW(nxt, dt + 1);     // next p-tile loads in flight

    bf16x8 pf[4];
#pragma unroll
    for (int kk = 0; kk < 4; ++kk)
      pf[kk] = pack8(cur[2 * kk], cur[2 * kk + 1]);

    f32x4 acc = (f32x4){0.f, 0.f, 0.f, 0.f};
#pragma unroll
    for (int kk = 0; kk < 4; ++kk)
      acc = __builtin_amdgcn_mfma_f32_16x16x32_bf16(pf[kk], qf[kk], acc, 0, 0, 0);

    // C/D layout: col = l16 = q, row = g*4 + reg = d-in-tile.
    // Tail tile clamps p-row to 179 -> duplicate values, max-safe, store-masked.
    qm = fmaxf(qm, fmaxf(fmaxf(acc[0], acc[1]), fmaxf(acc[2], acc[3])));
    const int d0 = dt * 16 + g * 4;
    if (d0 < D_N)   // only dt==11, g>0 masked
      *reinterpret_cast<f32x4*>(out + outbase + d0) = acc;
  }
#undef LOADRAW

  // max over the 4 g-groups (different d sub-rows, same q = l16)
  qm = fmaxf(qm, __shfl_xor(qm, 16, 64));
  qm = fmaxf(qm, __shfl_xor(qm, 32, 64));

  const size_t TERM_SZ = (size_t)A_N * B_N * Q_N * D_N;
  if (lane < 16)   // maxsim for q = qh*16 + lane
    out[TERM_SZ + ((size_t)a * B_N + b) * Q_N + qh * 16 + lane] = qm;

  // half-relevance: sum of this wave's 16 q-maxes (qm replicated across g)
  float s = qm;
  s += __shfl_xor(s, 1, 64);
  s += __shfl_xor(s, 2, 64);
  s += __shfl_xor(s, 4, 64);
  s += __shfl_xor(s, 8, 64);

  __shared__ float hs[2][2];   // [b-of-2][q-half]
  if (lane == 0) hs[wv >> 1][qh] = s;
  __syncthreads();             // only barrier: 2-float combine at block end

  if (tid < 2)
    out[TERM_SZ + (size_t)A_N * B_N * Q_N + (size_t)a * B_N + bg * 2 + tid] =
        hs[tid][0] + hs[tid][1];
}

extern "C" void kernel_launch(void* const* d_in, const int* in_sizes, int n_in,
                              void* d_out, int out_size, void* d_ws, size_t ws_size,
                              hipStream_t stream) {
  const float* q = (const float*)d_in[0];
  const float* p = (const float*)d_in[1];
  float* out = (float*)d_out;
  dim3 grid(4096);   // 64 bg x 64 a
  dim3 block(256);   // 4 independent waves: (b-of-2) x (q-half)
  hipLaunchKernelGGL(score_kernel, grid, block, 0, stream, q, p, out);
}

// Round 7
// 67.493 us; speedup vs baseline: 2.8891x; 2.8891x over previous
//
#include <hip/hip_runtime.h>
#include <hip/hip_bf16.h>

// RetrieverBase: q[64][32][128] f32, p[128][180][128] f32
// out = concat(term_relevance[64][128][32][180], query_maxsim[64][128][32], relevance[64][128])
#define A_N 64
#define B_N 128
#define Q_N 32
#define D_N 180
#define V_N 128

typedef __attribute__((ext_vector_type(8))) short bf16x8;   // 8 bf16 (4 VGPRs)
typedef __attribute__((ext_vector_type(4))) float f32x4;

__device__ __forceinline__ short f2bf(float f) {
  __hip_bfloat16 h = __float2bfloat16(f);
  return (short)__builtin_bit_cast(unsigned short, h);
}

__device__ __forceinline__ bf16x8 pack8(const f32x4& lo, const f32x4& hi) {
  bf16x8 v;
  v[0] = f2bf(lo[0]); v[1] = f2bf(lo[1]); v[2] = f2bf(lo[2]); v[3] = f2bf(lo[3]);
  v[4] = f2bf(hi[0]); v[5] = f2bf(hi[1]); v[6] = f2bf(hi[2]); v[7] = f2bf(hi[3]);
  return v;
}

// Grid 1024 = 8 ag x 128 b (b FAST: bid%8 == b%8, so each XCD only ever
// touches p-passages b = xcd (mod 8) -> 16 passages x 92KB f32 = 1.5MB,
// permanently L2-resident). Block = 512 thr = 8 waves, ONE b: stage p[b] as
// bf16 into LDS once (46KB, XOR-swizzled), one __syncthreads, then each wave
// independently computes the FULL C[32x180] = p[b]*q[a]^T for a = ag*8+wv.
//   - p fragments: ds_read_b128 (~12cy) -> no global-load stall chains
//   - stores flow straight from MFMA accs, no further barriers -> 16 waves/CU
//     keep continuous write pressure (R4 showed write BW scales with streams)
//   - one wave writes its whole 23KB (a,b) region in ~1us -> L2 merges the
//     720B-stride 16B chunks into full lines (R1/R3: exact WRITE_SIZE)
// LDS swizzle: row r = 16 chunks of 16B; phys slot = (s&8)|((s&7)^(r&7)).
// Fragment read (slot kk*4+g, rows dt*16+l16) -> 8 lanes per 4-bank group,
// perfectly balanced = conflict-free throughput.
__global__ __launch_bounds__(512, 4) void score_kernel(
    const float* __restrict__ q, const float* __restrict__ p,
    float* __restrict__ out) {
  const int bid  = blockIdx.x;
  const int b    = bid & (B_N - 1);
  const int ag   = bid >> 7;          // 0..7
  const int tid  = threadIdx.x;
  const int wv   = tid >> 6;          // 0..7
  const int lane = tid & 63;
  const int l16  = lane & 15;
  const int g    = lane >> 4;         // 0..3
  const int a    = ag * 8 + wv;

  const float* __restrict__ pb = p + (size_t)b * D_N * V_N;

  // ---- stage p[b] -> LDS bf16, swizzled: 2880 16B-chunks over 512 threads ----
  __shared__ ushort plds[D_N * V_N];   // 46080 B
  for (int c = tid; c < D_N * (V_N / 8); c += 512) {
    const int r  = c >> 4;
    const int s  = c & 15;
    const int sp = (s & 8) | ((s & 7) ^ (r & 7));
    const float* src = pb + (size_t)r * V_N + s * 8;
    *reinterpret_cast<bf16x8*>(&plds[r * V_N + sp * 8]) =
        pack8(*reinterpret_cast<const f32x4*>(src),
              *reinterpret_cast<const f32x4*>(src + 4));
  }

  // q as B-fragments for this wave's a (global; q is 1MB, L2/L3-resident):
  // B[k][col=q]; lane reads q[qt*16+l16][kk*32+g*8 ..+7]
  const float* __restrict__ qa = q + (size_t)a * Q_N * V_N;
  bf16x8 qf[2][4];
#pragma unroll
  for (int qt = 0; qt < 2; ++qt)
#pragma unroll
    for (int kk = 0; kk < 4; ++kk) {
      const float* s = qa + (size_t)(qt * 16 + l16) * V_N + kk * 32 + g * 8;
      qf[qt][kk] = pack8(*reinterpret_cast<const f32x4*>(s),
                         *reinterpret_cast<const f32x4*>(s + 4));
    }

  __syncthreads();   // staging complete — the ONLY barrier

  float qm0 = -INFINITY, qm1 = -INFINITY;
  const size_t outbase = ((size_t)a * B_N + b) * (size_t)(Q_N * D_N);

#pragma unroll
  for (int dt = 0; dt < 12; ++dt) {
    const int drow = dt * 16 + l16;
    const int dr   = drow < D_N ? drow : (D_N - 1);  // tail clamp, max-safe

    // A-fragments from LDS: p-row dr, k-chunk slot kk*4+g (swizzled)
    bf16x8 pf[4];
#pragma unroll
    for (int kk = 0; kk < 4; ++kk) {
      const int s  = kk * 4 + g;
      const int sp = (s & 8) | ((s & 7) ^ (dr & 7));
      pf[kk] = *reinterpret_cast<const bf16x8*>(&plds[dr * V_N + sp * 8]);
    }

    f32x4 acc0 = (f32x4){0.f, 0.f, 0.f, 0.f};
    f32x4 acc1 = (f32x4){0.f, 0.f, 0.f, 0.f};
#pragma unroll
    for (int kk = 0; kk < 4; ++kk) {
      acc0 = __builtin_amdgcn_mfma_f32_16x16x32_bf16(pf[kk], qf[0][kk], acc0, 0, 0, 0);
      acc1 = __builtin_amdgcn_mfma_f32_16x16x32_bf16(pf[kk], qf[1][kk], acc1, 0, 0, 0);
    }

    // C/D layout: col=l16=q, row=g*4+reg=d-in-tile; dt==11,g>0 masked (dups)
    qm0 = fmaxf(qm0, fmaxf(fmaxf(acc0[0], acc0[1]), fmaxf(acc0[2], acc0[3])));
    qm1 = fmaxf(qm1, fmaxf(fmaxf(acc1[0], acc1[1]), fmaxf(acc1[2], acc1[3])));
    const int d0 = dt * 16 + g * 4;
    if (d0 < D_N) {
      *reinterpret_cast<f32x4*>(out + outbase + (size_t)l16 * D_N + d0)        = acc0;
      *reinterpret_cast<f32x4*>(out + outbase + (size_t)(16 + l16) * D_N + d0) = acc1;
    }
  }

  // max across the 4 g-groups (different d sub-rows, same q)
  qm0 = fmaxf(qm0, __shfl_xor(qm0, 16, 64));
  qm0 = fmaxf(qm0, __shfl_xor(qm0, 32, 64));
  qm1 = fmaxf(qm1, __shfl_xor(qm1, 16, 64));
  qm1 = fmaxf(qm1, __shfl_xor(qm1, 32, 64));

  const size_t TERM_SZ = (size_t)A_N * B_N * Q_N * D_N;
  if (lane < 16) {   // maxsim for q = qt*16 + lane
    float* ms = out + TERM_SZ + ((size_t)a * B_N + b) * Q_N;
    ms[lane]      = qm0;
    ms[16 + lane] = qm1;
  }

  // relevance = sum over 32 q of maxsim (qm replicated across g-groups)
  float s = qm0 + qm1;
  s += __shfl_xor(s, 1, 64);
  s += __shfl_xor(s, 2, 64);
  s += __shfl_xor(s, 4, 64);
  s += __shfl_xor(s, 8, 64);
  if (lane == 0)
    out[TERM_SZ + (size_t)A_N * B_N * Q_N + (size_t)a * B_N + b] = s;
}

extern "C" void kernel_launch(void* const* d_in, const int* in_sizes, int n_in,
                              void* d_out, int out_size, void* d_ws, size_t ws_size,
                              hipStream_t stream) {
  const float* q = (const float*)d_in[0];
  const float* p = (const float*)d_in[1];
  float* out = (float*)d_out;
  dim3 grid(1024);   // 8 a-groups x 128 b (b fast -> XCD-stable p residency)
  dim3 block(512);   // 8 waves; stage p[b] once, then 8 independent (a,b) jobs
  hipLaunchKernelGGL(score_kernel, grid, block, 0, stream, q, p, out);
}